// Round 6
// baseline (204.753 us; speedup 1.0000x reference)
//
#include <hip/hip_runtime.h>

// NCC loss, win=9, (1,1,160,192,224) fp32 -> scalar. Fully fused, round 6.
// Pipelined wave-group stages, DCH=20, 3 blocks/CU (LDS 44.8 KB), 2 barriers/slice:
//   phase1: waves 0-2 (192t): W(i+1) global f4 loads, sliding 9-tap W-sums ->
//           SW[(i+1)&1] b128 (stride 36, proven 0-conflict)
//        || waves 3-5 (160t): H(i): 24 col-reads (ds_read2 pairs) over SW[i&1],
//           sliding 16 H-sums -> SH [row][col][ch] (ds_write2 pairs, delta 160dw)
//   barA;  F(i): all 512t read SH (read2 x2 + 1), O(1) D-ring, cc;  barB
// SH single-buffered: F(i) reads before barB, H(i+1) writes after barB.
// SW dbuf: H(i) reads vs W(i+2) writes separated by barA+barB.
// Ring phase-static via unroll-9 inner loop; 36 slots, live i<28 guarded.

#define DD 160
#define HH 192
#define WW 224
#define W4 56                 // WW/4
#define SLICE (HH * WW)
#define S4 (SLICE / 4)
#define NVOX (DD * SLICE)
#define TW 32
#define TH 16
#define DCH 20                // grid.z = 8 -> 672 blocks
#define ITERS (DCH + 8)       // 28
#define NTHR 512
#define SW_RS 36              // b128-aligned rows; 0-conflict measured (R5)
#define SW_CS (24 * SW_RS)    // 864
#define EPS 1e-5f
#define INV_WSUM (1.0f / 729.0f)

__global__ __launch_bounds__(NTHR, 6) void ncc_fused(const float* __restrict__ I,
                                                     const float* __restrict__ J,
                                                     float* __restrict__ out) {
    __shared__ float SW0[5 * SW_CS], SW1[5 * SW_CS];   // 17.28 KB each
    __shared__ float SH[TH * TW * 5];                  // 10.24 KB, [row][col][ch]
    __shared__ float wred[NTHR / 64];

    const int tid = threadIdx.x;
    const int tx = tid & 31, ty = tid >> 5;
    const int wlo = blockIdx.x * TW;
    const int hlo = blockIdx.y * TH;
    const int dlo = blockIdx.z * DCH;

    // W-group (tid < 192): 24 rows x 8 f4-col groups
    const int wr = tid >> 3, wc = tid & 7;
    const int gh = hlo - 4 + wr;
    const bool hok = (gh >= 0) && (gh < HH);
    const int gf0 = (wlo >> 2) - 1 + wc;

    // H-group (tid in [192,352)): 5 channels x 32 cols
    const int ht = tid - 192;
    const int hcol = ht & 31, hch = ht >> 5;

    const float4* Iv = (const float4*)I;
    const float4* Jv = (const float4*)J;

    auto w_stage = [&](int z, float* dst) {
        const int rowb = z * S4 + gh * W4;
        float ax[12], bx[12];
        #pragma unroll
        for (int k = 0; k < 3; ++k) {
            const int f = gf0 + k;
            float4 a = make_float4(0.f, 0.f, 0.f, 0.f);
            float4 b = make_float4(0.f, 0.f, 0.f, 0.f);
            if (hok && f >= 0 && f < W4) { a = Iv[rowb + f]; b = Jv[rowb + f]; }
            ax[4*k] = a.x; ax[4*k+1] = a.y; ax[4*k+2] = a.z; ax[4*k+3] = a.w;
            bx[4*k] = b.x; bx[4*k+1] = b.y; bx[4*k+2] = b.z; bx[4*k+3] = b.w;
        }
        float* wp = dst + wr * SW_RS + 4 * wc;
        #pragma unroll
        for (int ch = 0; ch < 5; ++ch) {
            float v[12];
            #pragma unroll
            for (int k = 0; k < 12; ++k)
                v[k] = (ch == 0) ? ax[k]
                     : (ch == 1) ? bx[k]
                     : (ch == 2) ? ax[k] * ax[k]
                     : (ch == 3) ? bx[k] * bx[k]
                     :             ax[k] * bx[k];
            float s = v[0];
            #pragma unroll
            for (int k = 1; k < 9; ++k) s += v[k];
            float4 o;
            o.x = s;
            s += v[9]  - v[0]; o.y = s;
            s += v[10] - v[1]; o.z = s;
            s += v[11] - v[2]; o.w = s;
            *(float4*)(wp + ch * SW_CS) = o;   // b128, 16B-aligned
        }
    };

    float q0[9], q1[9], q2[9], q3[9], q4[9];
    #pragma unroll
    for (int k = 0; k < 9; ++k) { q0[k]=0.f; q1[k]=0.f; q2[k]=0.f; q3[k]=0.f; q4[k]=0.f; }
    float r0=0.f, r1=0.f, r2=0.f, r3=0.f, r4=0.f;
    float acc = 0.f;

    // prologue: stage z0 = dlo-4 into SW0
    if (tid < 192 && dlo >= 4) w_stage(dlo - 4, SW0);
    __syncthreads();

    #pragma unroll 1
    for (int g = 0; g < 4; ++g) {
        #pragma unroll
        for (int ph = 0; ph < 9; ++ph) {
            const int i = 9 * g + ph;
            const int z = dlo - 4 + i;
            const bool live = (i < ITERS);
            const bool val = live && (z >= 0) && (z < DD);   // block-uniform
            const int par = i & 1;
            float* swR = par ? SW1 : SW0;
            float* swW = par ? SW0 : SW1;

            if (tid < 192) {
                const int zn = z + 1;
                if (i < ITERS - 1 && zn >= 0 && zn < DD) w_stage(zn, swW);
            } else if (ht < 160 && val) {
                const float* p = swR + hch * SW_CS + hcol;
                float v[24];
                #pragma unroll
                for (int r = 0; r < 24; r += 2) {       // pairs -> ds_read2_b32
                    const float* pr = p + r * SW_RS;
                    v[r]     = pr[0];
                    v[r + 1] = pr[SW_RS];
                }
                float s = v[0];
                #pragma unroll
                for (int r = 1; r < 9; ++r) s += v[r];
                float* o = SH + hcol * 5 + hch;         // [row][col][ch]
                float prev = s;
                o[0] = s;
                #pragma unroll
                for (int r = 1; r < 16; ++r) {
                    prev += v[r + 8] - v[r - 1];
                    o[r * (TW * 5)] = prev;             // delta 160 dw -> ds_write2
                }
            }
            __syncthreads();   // barA: SH(i) visible to F

            float w0=0.f, w1=0.f, w2=0.f, w3=0.f, w4=0.f;
            if (val) {
                const float* p = SH + (ty * TW + tx) * 5;
                w0 = p[0]; w1 = p[1]; w2 = p[2]; w3 = p[3]; w4 = p[4];
            }
            r0 += w0 - q0[ph]; q0[ph] = w0;
            r1 += w1 - q1[ph]; q1[ph] = w1;
            r2 += w2 - q2[ph]; q2[ph] = w2;
            r3 += w3 - q3[ph]; q3[ph] = w3;
            r4 += w4 - q4[ph]; q4[ph] = w4;

            if (live && i >= 8) {
                float cross = r4 - r0 * r1 * INV_WSUM;
                float iv    = r2 - r0 * r0 * INV_WSUM;
                float jv    = r3 - r1 * r1 * INV_WSUM;
                acc += cross * cross * __builtin_amdgcn_rcpf(iv * jv + EPS);
            }
            __syncthreads();   // barB: F done with SH; H(i+1)/W(i+2) may proceed
        }
    }

    // ---- block reduction -> one atomic ----
    #pragma unroll
    for (int off = 32; off > 0; off >>= 1) acc += __shfl_down(acc, off, 64);
    if ((tid & 63) == 0) wred[tid >> 6] = acc;
    __syncthreads();
    if (tid == 0) {
        float t = 0.f;
        #pragma unroll
        for (int k = 0; k < NTHR / 64; ++k) t += wred[k];
        atomicAdd(out, t * (-1.0f / (float)NVOX));
    }
}

extern "C" void kernel_launch(void* const* d_in, const int* in_sizes, int n_in,
                              void* d_out, int out_size, void* d_ws, size_t ws_size,
                              hipStream_t stream) {
    const float* I = (const float*)d_in[0];
    const float* J = (const float*)d_in[1];
    float* out = (float*)d_out;

    hipMemsetAsync(d_out, 0, sizeof(float), stream);  // harness re-poisons d_out

    dim3 blk(NTHR, 1, 1);
    dim3 grd(WW / TW, HH / TH, DD / DCH);             // 7 x 12 x 8 = 672 blocks
    ncc_fused<<<grd, blk, 0, stream>>>(I, J, out);
}

// Round 7
// 138.764 us; speedup vs baseline: 1.4755x; 1.4755x over previous
//
#include <hip/hip_runtime.h>

// NCC loss, win=9, (1,1,160,192,224) fp32 -> scalar. Fully fused, round 7.
// == Round 6 structure with the ONE fix: __launch_bounds__(512,4) (R6's (,6)
// forced a 40-VGPR cap -> 111 MB scratch spill, 2x regression).
// Pipelined wave-group stages, DCH=20, LDS 44.8 KB (3 blocks/CU possible),
// 2 barriers/slice:
//   phase1: waves 0-2 (192t): W(i+1) global f4 loads, sliding 9-tap W-sums ->
//           SW[(i+1)&1] b128 (stride 36, 0-conflict measured)
//        || waves 3-5 (160t): H(i): 24 paired col-reads over SW[i&1],
//           sliding 16 H-sums -> SH [row][col][ch] (paired writes, delta 160dw)
//   barA;  F(i): all 512t read SH (5 b32), O(1) D-ring, cc;  barB
// SH single-buffered: F(i) reads before barB, H(i+1) writes after barB.
// SW dbuf: H(i) reads vs W(i+2) writes separated by barA+barB.

#define DD 160
#define HH 192
#define WW 224
#define W4 56                 // WW/4
#define SLICE (HH * WW)
#define S4 (SLICE / 4)
#define NVOX (DD * SLICE)
#define TW 32
#define TH 16
#define DCH 20                // grid.z = 8 -> 672 blocks
#define ITERS (DCH + 8)       // 28
#define NTHR 512
#define SW_RS 36              // b128-aligned rows; 0-conflict measured (R5)
#define SW_CS (24 * SW_RS)    // 864
#define EPS 1e-5f
#define INV_WSUM (1.0f / 729.0f)

__global__ __launch_bounds__(NTHR, 4) void ncc_fused(const float* __restrict__ I,
                                                     const float* __restrict__ J,
                                                     float* __restrict__ out) {
    __shared__ float SW0[5 * SW_CS], SW1[5 * SW_CS];   // 17.28 KB each
    __shared__ float SH[TH * TW * 5];                  // 10.24 KB, [row][col][ch]
    __shared__ float wred[NTHR / 64];

    const int tid = threadIdx.x;
    const int tx = tid & 31, ty = tid >> 5;
    const int wlo = blockIdx.x * TW;
    const int hlo = blockIdx.y * TH;
    const int dlo = blockIdx.z * DCH;

    // W-group (tid < 192): 24 rows x 8 f4-col groups
    const int wr = tid >> 3, wc = tid & 7;
    const int gh = hlo - 4 + wr;
    const bool hok = (gh >= 0) && (gh < HH);
    const int gf0 = (wlo >> 2) - 1 + wc;

    // H-group (tid in [192,352)): 5 channels x 32 cols
    const int ht = tid - 192;
    const int hcol = ht & 31, hch = ht >> 5;

    const float4* Iv = (const float4*)I;
    const float4* Jv = (const float4*)J;

    auto w_stage = [&](int z, float* dst) {
        const int rowb = z * S4 + gh * W4;
        float ax[12], bx[12];
        #pragma unroll
        for (int k = 0; k < 3; ++k) {
            const int f = gf0 + k;
            float4 a = make_float4(0.f, 0.f, 0.f, 0.f);
            float4 b = make_float4(0.f, 0.f, 0.f, 0.f);
            if (hok && f >= 0 && f < W4) { a = Iv[rowb + f]; b = Jv[rowb + f]; }
            ax[4*k] = a.x; ax[4*k+1] = a.y; ax[4*k+2] = a.z; ax[4*k+3] = a.w;
            bx[4*k] = b.x; bx[4*k+1] = b.y; bx[4*k+2] = b.z; bx[4*k+3] = b.w;
        }
        float* wp = dst + wr * SW_RS + 4 * wc;
        #pragma unroll
        for (int ch = 0; ch < 5; ++ch) {
            float v[12];
            #pragma unroll
            for (int k = 0; k < 12; ++k)
                v[k] = (ch == 0) ? ax[k]
                     : (ch == 1) ? bx[k]
                     : (ch == 2) ? ax[k] * ax[k]
                     : (ch == 3) ? bx[k] * bx[k]
                     :             ax[k] * bx[k];
            float s = v[0];
            #pragma unroll
            for (int k = 1; k < 9; ++k) s += v[k];
            float4 o;
            o.x = s;
            s += v[9]  - v[0]; o.y = s;
            s += v[10] - v[1]; o.z = s;
            s += v[11] - v[2]; o.w = s;
            *(float4*)(wp + ch * SW_CS) = o;   // b128, 16B-aligned
        }
    };

    float q0[9], q1[9], q2[9], q3[9], q4[9];
    #pragma unroll
    for (int k = 0; k < 9; ++k) { q0[k]=0.f; q1[k]=0.f; q2[k]=0.f; q3[k]=0.f; q4[k]=0.f; }
    float r0=0.f, r1=0.f, r2=0.f, r3=0.f, r4=0.f;
    float acc = 0.f;

    // prologue: stage z0 = dlo-4 into SW0
    if (tid < 192 && dlo >= 4) w_stage(dlo - 4, SW0);
    __syncthreads();

    #pragma unroll 1
    for (int g = 0; g < 4; ++g) {
        #pragma unroll
        for (int ph = 0; ph < 9; ++ph) {
            const int i = 9 * g + ph;
            const int z = dlo - 4 + i;
            const bool live = (i < ITERS);
            const bool val = live && (z >= 0) && (z < DD);   // block-uniform
            const int par = i & 1;
            float* swR = par ? SW1 : SW0;
            float* swW = par ? SW0 : SW1;

            if (tid < 192) {
                const int zn = z + 1;
                if (i < ITERS - 1 && zn >= 0 && zn < DD) w_stage(zn, swW);
            } else if (ht < 160 && val) {
                const float* p = swR + hch * SW_CS + hcol;
                float v[24];
                #pragma unroll
                for (int r = 0; r < 24; r += 2) {       // pairs -> ds_read2_b32
                    const float* pr = p + r * SW_RS;
                    v[r]     = pr[0];
                    v[r + 1] = pr[SW_RS];
                }
                float s = v[0];
                #pragma unroll
                for (int r = 1; r < 9; ++r) s += v[r];
                float* o = SH + hcol * 5 + hch;         // [row][col][ch]
                float prev = s;
                o[0] = s;
                #pragma unroll
                for (int r = 1; r < 16; ++r) {
                    prev += v[r + 8] - v[r - 1];
                    o[r * (TW * 5)] = prev;             // delta 160 dw -> ds_write2
                }
            }
            __syncthreads();   // barA: SH(i) visible to F

            float w0=0.f, w1=0.f, w2=0.f, w3=0.f, w4=0.f;
            if (val) {
                const float* p = SH + (ty * TW + tx) * 5;
                w0 = p[0]; w1 = p[1]; w2 = p[2]; w3 = p[3]; w4 = p[4];
            }
            r0 += w0 - q0[ph]; q0[ph] = w0;
            r1 += w1 - q1[ph]; q1[ph] = w1;
            r2 += w2 - q2[ph]; q2[ph] = w2;
            r3 += w3 - q3[ph]; q3[ph] = w3;
            r4 += w4 - q4[ph]; q4[ph] = w4;

            if (live && i >= 8) {
                float cross = r4 - r0 * r1 * INV_WSUM;
                float iv    = r2 - r0 * r0 * INV_WSUM;
                float jv    = r3 - r1 * r1 * INV_WSUM;
                acc += cross * cross * __builtin_amdgcn_rcpf(iv * jv + EPS);
            }
            __syncthreads();   // barB: F done with SH; H(i+1)/W(i+2) may proceed
        }
    }

    // ---- block reduction -> one atomic ----
    #pragma unroll
    for (int off = 32; off > 0; off >>= 1) acc += __shfl_down(acc, off, 64);
    if ((tid & 63) == 0) wred[tid >> 6] = acc;
    __syncthreads();
    if (tid == 0) {
        float t = 0.f;
        #pragma unroll
        for (int k = 0; k < NTHR / 64; ++k) t += wred[k];
        atomicAdd(out, t * (-1.0f / (float)NVOX));
    }
}

extern "C" void kernel_launch(void* const* d_in, const int* in_sizes, int n_in,
                              void* d_out, int out_size, void* d_ws, size_t ws_size,
                              hipStream_t stream) {
    const float* I = (const float*)d_in[0];
    const float* J = (const float*)d_in[1];
    float* out = (float*)d_out;

    hipMemsetAsync(d_out, 0, sizeof(float), stream);  // harness re-poisons d_out

    dim3 blk(NTHR, 1, 1);
    dim3 grd(WW / TW, HH / TH, DD / DCH);             // 7 x 12 x 8 = 672 blocks
    ncc_fused<<<grd, blk, 0, stream>>>(I, J, out);
}

// Round 8
// 137.519 us; speedup vs baseline: 1.4889x; 1.0091x over previous
//
#include <hip/hip_runtime.h>

// NCC loss, win=9, (1,1,160,192,224) fp32 -> scalar. Fully fused, round 8.
// R7 structure + (a) W-stage REGISTER PREFETCH one slice ahead (consume-then-
// refill, 24 persistent VGPRs) so the ~900-cyc cold-HBM load latency is off
// the per-slice critical path, and (b) DCH=19 -> ITERS=27=3x9 exactly (no dead
// iterations; 756 blocks, all co-resident at 3 blocks/CU by LDS).
//   phase1: waves 0-2 (192t): W(i+1) slide from prefetched regs -> SW[(i+1)&1]
//           (b128, stride 36, 0-conflict); then issue loads for slice z+2.
//        || waves 3-5 (160t): H(i) paired col-reads over SW[i&1] -> SH.
//   barA;  F(i): 512t read SH (5 b32), O(1) D-ring, cc (guard d<DD);  barB.
// SH single-buffered (F(i) reads pre-barB, H(i+1) writes post-barB);
// SW dbuf (H(i) reads vs W(i+2) writes separated by barA+barB).

#define DD 160
#define HH 192
#define WW 224
#define W4 56                 // WW/4
#define SLICE (HH * WW)
#define S4 (SLICE / 4)
#define NVOX (DD * SLICE)
#define TW 32
#define TH 16
#define DCH 19                // grid.z = 9 -> 756 blocks (<=768 = 3/CU * 256)
#define ITERS (DCH + 8)       // 27 = 3 * 9 exactly
#define NTHR 512
#define SW_RS 36              // b128-aligned rows; 0-conflict measured (R5/R7)
#define SW_CS (24 * SW_RS)    // 864
#define EPS 1e-5f
#define INV_WSUM (1.0f / 729.0f)

__global__ __launch_bounds__(NTHR, 4) void ncc_fused(const float* __restrict__ I,
                                                     const float* __restrict__ J,
                                                     float* __restrict__ out) {
    __shared__ float SW0[5 * SW_CS], SW1[5 * SW_CS];   // 17.28 KB each
    __shared__ float SH[TH * TW * 5];                  // 10.24 KB, [row][col][ch]
    __shared__ float wred[NTHR / 64];

    const int tid = threadIdx.x;
    const int tx = tid & 31, ty = tid >> 5;
    const int wlo = blockIdx.x * TW;
    const int hlo = blockIdx.y * TH;
    const int dlo = blockIdx.z * DCH;

    // W-group (tid < 192): 24 rows x 8 f4-col groups
    const int wr = tid >> 3, wc = tid & 7;
    const int gh = hlo - 4 + wr;
    const bool hok = (gh >= 0) && (gh < HH);
    const int gf0 = (wlo >> 2) - 1 + wc;

    // H-group (tid in [192,352)): 5 channels x 32 cols
    const int ht = tid - 192;
    const int hcol = ht & 31, hch = ht >> 5;

    const float4* Iv = (const float4*)I;
    const float4* Jv = (const float4*)J;

    // prefetch registers: one slice of raw I/J (12 floats each)
    float pfa[12], pfb[12];

    auto w_load = [&](int z) {   // fill pfa/pfb for slice z (zeros if OOB)
        const bool zok = (z >= 0) && (z < DD) && hok;
        const int rowb = z * S4 + gh * W4;
        #pragma unroll
        for (int k = 0; k < 3; ++k) {
            const int f = gf0 + k;
            float4 a = make_float4(0.f, 0.f, 0.f, 0.f);
            float4 b = make_float4(0.f, 0.f, 0.f, 0.f);
            if (zok && f >= 0 && f < W4) { a = Iv[rowb + f]; b = Jv[rowb + f]; }
            pfa[4*k] = a.x; pfa[4*k+1] = a.y; pfa[4*k+2] = a.z; pfa[4*k+3] = a.w;
            pfb[4*k] = b.x; pfb[4*k+1] = b.y; pfb[4*k+2] = b.z; pfb[4*k+3] = b.w;
        }
    };

    auto w_compute = [&](float* dst) {   // slide 9-tap W-sums from pfa/pfb -> dst
        float* wp = dst + wr * SW_RS + 4 * wc;
        #pragma unroll
        for (int ch = 0; ch < 5; ++ch) {
            float v[12];
            #pragma unroll
            for (int k = 0; k < 12; ++k)
                v[k] = (ch == 0) ? pfa[k]
                     : (ch == 1) ? pfb[k]
                     : (ch == 2) ? pfa[k] * pfa[k]
                     : (ch == 3) ? pfb[k] * pfb[k]
                     :             pfa[k] * pfb[k];
            float s = v[0];
            #pragma unroll
            for (int k = 1; k < 9; ++k) s += v[k];
            float4 o;
            o.x = s;
            s += v[9]  - v[0]; o.y = s;
            s += v[10] - v[1]; o.z = s;
            s += v[11] - v[2]; o.w = s;
            *(float4*)(wp + ch * SW_CS) = o;   // b128, 16B-aligned
        }
    };

    float q0[9], q1[9], q2[9], q3[9], q4[9];
    #pragma unroll
    for (int k = 0; k < 9; ++k) { q0[k]=0.f; q1[k]=0.f; q2[k]=0.f; q3[k]=0.f; q4[k]=0.f; }
    float r0=0.f, r1=0.f, r2=0.f, r3=0.f, r4=0.f;
    float acc = 0.f;

    // prologue: slice z0 = dlo-4 -> SW0; then prefetch z1 = dlo-3
    if (tid < 192) {
        w_load(dlo - 4);
        if (dlo >= 4) w_compute(SW0);       // z0 < DD always (dlo <= 152)
        w_load(dlo - 3);
    }
    __syncthreads();

    #pragma unroll 1
    for (int g = 0; g < 3; ++g) {
        #pragma unroll
        for (int ph = 0; ph < 9; ++ph) {
            const int i = 9 * g + ph;
            const int z = dlo - 4 + i;
            const bool val = (z >= 0) && (z < DD);   // block-uniform
            const int par = i & 1;
            float* swR = par ? SW1 : SW0;
            float* swW = par ? SW0 : SW1;

            if (tid < 192) {
                if (i < ITERS - 1) {
                    const int zn = z + 1;
                    if (zn >= 0 && zn < DD) w_compute(swW);  // consume prefetch
                    w_load(z + 2);                           // refill for i+1
                }
            } else if (ht < 160 && val) {
                const float* p = swR + hch * SW_CS + hcol;
                float v[24];
                #pragma unroll
                for (int r = 0; r < 24; r += 2) {       // pairs -> ds_read2_b32
                    const float* pr = p + r * SW_RS;
                    v[r]     = pr[0];
                    v[r + 1] = pr[SW_RS];
                }
                float s = v[0];
                #pragma unroll
                for (int r = 1; r < 9; ++r) s += v[r];
                float* o = SH + hcol * 5 + hch;         // [row][col][ch]
                float prev = s;
                o[0] = s;
                #pragma unroll
                for (int r = 1; r < 16; ++r) {
                    prev += v[r + 8] - v[r - 1];
                    o[r * (TW * 5)] = prev;
                }
            }
            __syncthreads();   // barA: SH(i) visible to F

            float w0=0.f, w1=0.f, w2=0.f, w3=0.f, w4=0.f;
            if (val) {
                const float* p = SH + (ty * TW + tx) * 5;
                w0 = p[0]; w1 = p[1]; w2 = p[2]; w3 = p[3]; w4 = p[4];
            }
            r0 += w0 - q0[ph]; q0[ph] = w0;
            r1 += w1 - q1[ph]; q1[ph] = w1;
            r2 += w2 - q2[ph]; q2[ph] = w2;
            r3 += w3 - q3[ph]; q3[ph] = w3;
            r4 += w4 - q4[ph]; q4[ph] = w4;

            if (i >= 8 && (dlo + i - 8) < DD) {   // last chunk overhangs to 171
                float cross = r4 - r0 * r1 * INV_WSUM;
                float iv    = r2 - r0 * r0 * INV_WSUM;
                float jv    = r3 - r1 * r1 * INV_WSUM;
                acc += cross * cross * __builtin_amdgcn_rcpf(iv * jv + EPS);
            }
            __syncthreads();   // barB: F done with SH; H(i+1)/W(i+2) may proceed
        }
    }

    // ---- block reduction -> one atomic ----
    #pragma unroll
    for (int off = 32; off > 0; off >>= 1) acc += __shfl_down(acc, off, 64);
    if ((tid & 63) == 0) wred[tid >> 6] = acc;
    __syncthreads();
    if (tid == 0) {
        float t = 0.f;
        #pragma unroll
        for (int k = 0; k < NTHR / 64; ++k) t += wred[k];
        atomicAdd(out, t * (-1.0f / (float)NVOX));
    }
}

extern "C" void kernel_launch(void* const* d_in, const int* in_sizes, int n_in,
                              void* d_out, int out_size, void* d_ws, size_t ws_size,
                              hipStream_t stream) {
    const float* I = (const float*)d_in[0];
    const float* J = (const float*)d_in[1];
    float* out = (float*)d_out;

    hipMemsetAsync(d_out, 0, sizeof(float), stream);  // harness re-poisons d_out

    dim3 blk(NTHR, 1, 1);
    dim3 grd(WW / TW, HH / TH, (DD + DCH - 1) / DCH); // 7 x 12 x 9 = 756 blocks
    ncc_fused<<<grd, blk, 0, stream>>>(I, J, out);
}

// Round 9
// 136.809 us; speedup vs baseline: 1.4966x; 1.0052x over previous
//
#include <hip/hip_runtime.h>

// NCC loss, win=9, (1,1,160,192,224) fp32 -> scalar. Fully fused, round 9.
// == R8 with ONE change: in-loop barriers are raw `s_waitcnt lgkmcnt(0);
// s_barrier` (vmcnt UNCONSTRAINED). __syncthreads() emits s_waitcnt vmcnt(0)
// which drained the W-waves' global register-prefetch at every barrier
// (~1k cyc/slice stall for the whole block) — defeating R8's prefetch.
// The barriers only order LDS (SW/SH); pf regs are private and protected by
// the compiler's own vmcnt wait before first use in w_compute.
//   phase1: waves 0-2 (192t): W(i+1) slide from prefetched regs -> SW[(i+1)&1]
//           (b128, stride 36, 0-conflict); then issue loads for slice z+2.
//        || waves 3-5 (160t): H(i) paired col-reads over SW[i&1] -> SH.
//   barA;  F(i): 512t read SH (5 b32), O(1) D-ring, cc (guard d<DD);  barB.
// SH single-buffered (F(i) pre-barB, H(i+1) post-barB); SW dbuf.
// DCH=19 -> ITERS=27=3x9 (phase-static ring), 756 blocks.

#define DD 160
#define HH 192
#define WW 224
#define W4 56                 // WW/4
#define SLICE (HH * WW)
#define S4 (SLICE / 4)
#define NVOX (DD * SLICE)
#define TW 32
#define TH 16
#define DCH 19                // grid.z = 9 -> 756 blocks
#define ITERS (DCH + 8)       // 27 = 3 * 9 exactly
#define NTHR 512
#define SW_RS 36              // b128-aligned rows; 0-conflict measured (R5/R7)
#define SW_CS (24 * SW_RS)    // 864
#define EPS 1e-5f
#define INV_WSUM (1.0f / 729.0f)

// Barrier that orders LDS only: s_waitcnt imm 0xC07F = lgkmcnt(0), vmcnt(63),
// expcnt(7) -> in-flight GLOBAL loads stay in flight across the barrier.
__device__ __forceinline__ void bar_lds_only() {
    __asm__ volatile("" ::: "memory");
    __builtin_amdgcn_s_waitcnt(0xC07F);
    __builtin_amdgcn_s_barrier();
    __asm__ volatile("" ::: "memory");
}

__global__ __launch_bounds__(NTHR, 4) void ncc_fused(const float* __restrict__ I,
                                                     const float* __restrict__ J,
                                                     float* __restrict__ out) {
    __shared__ float SW0[5 * SW_CS], SW1[5 * SW_CS];   // 17.28 KB each
    __shared__ float SH[TH * TW * 5];                  // 10.24 KB, [row][col][ch]
    __shared__ float wred[NTHR / 64];

    const int tid = threadIdx.x;
    const int tx = tid & 31, ty = tid >> 5;
    const int wlo = blockIdx.x * TW;
    const int hlo = blockIdx.y * TH;
    const int dlo = blockIdx.z * DCH;

    // W-group (tid < 192): 24 rows x 8 f4-col groups
    const int wr = tid >> 3, wc = tid & 7;
    const int gh = hlo - 4 + wr;
    const bool hok = (gh >= 0) && (gh < HH);
    const int gf0 = (wlo >> 2) - 1 + wc;

    // H-group (tid in [192,352)): 5 channels x 32 cols
    const int ht = tid - 192;
    const int hcol = ht & 31, hch = ht >> 5;

    const float4* Iv = (const float4*)I;
    const float4* Jv = (const float4*)J;

    // prefetch registers: one slice of raw I/J (12 floats each)
    float pfa[12], pfb[12];

    auto w_load = [&](int z) {   // fill pfa/pfb for slice z (zeros if OOB)
        const bool zok = (z >= 0) && (z < DD) && hok;
        const int rowb = z * S4 + gh * W4;
        #pragma unroll
        for (int k = 0; k < 3; ++k) {
            const int f = gf0 + k;
            float4 a = make_float4(0.f, 0.f, 0.f, 0.f);
            float4 b = make_float4(0.f, 0.f, 0.f, 0.f);
            if (zok && f >= 0 && f < W4) { a = Iv[rowb + f]; b = Jv[rowb + f]; }
            pfa[4*k] = a.x; pfa[4*k+1] = a.y; pfa[4*k+2] = a.z; pfa[4*k+3] = a.w;
            pfb[4*k] = b.x; pfb[4*k+1] = b.y; pfb[4*k+2] = b.z; pfb[4*k+3] = b.w;
        }
    };

    auto w_compute = [&](float* dst) {   // slide 9-tap W-sums from pfa/pfb -> dst
        float* wp = dst + wr * SW_RS + 4 * wc;
        #pragma unroll
        for (int ch = 0; ch < 5; ++ch) {
            float v[12];
            #pragma unroll
            for (int k = 0; k < 12; ++k)
                v[k] = (ch == 0) ? pfa[k]
                     : (ch == 1) ? pfb[k]
                     : (ch == 2) ? pfa[k] * pfa[k]
                     : (ch == 3) ? pfb[k] * pfb[k]
                     :             pfa[k] * pfb[k];
            float s = v[0];
            #pragma unroll
            for (int k = 1; k < 9; ++k) s += v[k];
            float4 o;
            o.x = s;
            s += v[9]  - v[0]; o.y = s;
            s += v[10] - v[1]; o.z = s;
            s += v[11] - v[2]; o.w = s;
            *(float4*)(wp + ch * SW_CS) = o;   // b128, 16B-aligned
        }
    };

    float q0[9], q1[9], q2[9], q3[9], q4[9];
    #pragma unroll
    for (int k = 0; k < 9; ++k) { q0[k]=0.f; q1[k]=0.f; q2[k]=0.f; q3[k]=0.f; q4[k]=0.f; }
    float r0=0.f, r1=0.f, r2=0.f, r3=0.f, r4=0.f;
    float acc = 0.f;

    // prologue: slice z0 = dlo-4 -> SW0; then prefetch z1 = dlo-3
    if (tid < 192) {
        w_load(dlo - 4);
        if (dlo >= 4) w_compute(SW0);       // z0 < DD always (dlo <= 152)
        w_load(dlo - 3);
    }
    bar_lds_only();

    #pragma unroll 1
    for (int g = 0; g < 3; ++g) {
        #pragma unroll
        for (int ph = 0; ph < 9; ++ph) {
            const int i = 9 * g + ph;
            const int z = dlo - 4 + i;
            const bool val = (z >= 0) && (z < DD);   // block-uniform
            const int par = i & 1;
            float* swR = par ? SW1 : SW0;
            float* swW = par ? SW0 : SW1;

            if (tid < 192) {
                if (i < ITERS - 1) {
                    const int zn = z + 1;
                    if (zn >= 0 && zn < DD) w_compute(swW);  // consume prefetch
                    w_load(z + 2);                           // refill for i+1
                }
            } else if (ht < 160 && val) {
                const float* p = swR + hch * SW_CS + hcol;
                float v[24];
                #pragma unroll
                for (int r = 0; r < 24; r += 2) {       // pairs -> ds_read2_b32
                    const float* pr = p + r * SW_RS;
                    v[r]     = pr[0];
                    v[r + 1] = pr[SW_RS];
                }
                float s = v[0];
                #pragma unroll
                for (int r = 1; r < 9; ++r) s += v[r];
                float* o = SH + hcol * 5 + hch;         // [row][col][ch]
                float prev = s;
                o[0] = s;
                #pragma unroll
                for (int r = 1; r < 16; ++r) {
                    prev += v[r + 8] - v[r - 1];
                    o[r * (TW * 5)] = prev;
                }
            }
            bar_lds_only();    // barA: SH(i) visible to F (LDS-only ordering)

            float w0=0.f, w1=0.f, w2=0.f, w3=0.f, w4=0.f;
            if (val) {
                const float* p = SH + (ty * TW + tx) * 5;
                w0 = p[0]; w1 = p[1]; w2 = p[2]; w3 = p[3]; w4 = p[4];
            }
            r0 += w0 - q0[ph]; q0[ph] = w0;
            r1 += w1 - q1[ph]; q1[ph] = w1;
            r2 += w2 - q2[ph]; q2[ph] = w2;
            r3 += w3 - q3[ph]; q3[ph] = w3;
            r4 += w4 - q4[ph]; q4[ph] = w4;

            if (i >= 8 && (dlo + i - 8) < DD) {   // last chunk overhangs to 171
                float cross = r4 - r0 * r1 * INV_WSUM;
                float iv    = r2 - r0 * r0 * INV_WSUM;
                float jv    = r3 - r1 * r1 * INV_WSUM;
                acc += cross * cross * __builtin_amdgcn_rcpf(iv * jv + EPS);
            }
            bar_lds_only();    // barB: F done with SH; H(i+1)/W(i+2) may proceed
        }
    }

    // ---- block reduction -> one atomic (cold path: full __syncthreads ok) ----
    #pragma unroll
    for (int off = 32; off > 0; off >>= 1) acc += __shfl_down(acc, off, 64);
    if ((tid & 63) == 0) wred[tid >> 6] = acc;
    __syncthreads();
    if (tid == 0) {
        float t = 0.f;
        #pragma unroll
        for (int k = 0; k < NTHR / 64; ++k) t += wred[k];
        atomicAdd(out, t * (-1.0f / (float)NVOX));
    }
}

extern "C" void kernel_launch(void* const* d_in, const int* in_sizes, int n_in,
                              void* d_out, int out_size, void* d_ws, size_t ws_size,
                              hipStream_t stream) {
    const float* I = (const float*)d_in[0];
    const float* J = (const float*)d_in[1];
    float* out = (float*)d_out;

    hipMemsetAsync(d_out, 0, sizeof(float), stream);  // harness re-poisons d_out

    dim3 blk(NTHR, 1, 1);
    dim3 grd(WW / TW, HH / TH, (DD + DCH - 1) / DCH); // 7 x 12 x 9 = 756 blocks
    ncc_fused<<<grd, blk, 0, stream>>>(I, J, out);
}